// Round 7
// baseline (108.660 us; speedup 1.0000x reference)
//
#include <hip/hip_runtime.h>

// NEAT windowed-DAG forward:
//   values[0:16] = x; for i in 0..511: v = tanh(dot(values[i:i+16], w[i]) + b[i]) * r[i]
//   out = values[T-64:T]  (nodes 448..511)
//
// R7: R6 hit the LDS-pipe wall: 2 waves/CU x 5 ds_read_b128/node ~=120cyc/node
// on the shared pipe (VALU only ~56/wave). Fix: (a) 2 batch elements per
// thread, 1 wave/CU -> param reads amortized, LDS pipe load halves to 60;
// (b) float2 + __builtin_elementwise_fma -> v_pk_fma_f32 (gfx950 full-rate
// packed f32) so the doubled dot-product issue is halved back to ~36 cyc.
// Keeps R6's hand-pinned volatile-asm ds_read pipeline (depth 3, lgkmcnt(15)).

typedef float v4f __attribute__((ext_vector_type(4)));
typedef float v2f __attribute__((ext_vector_type(2)));

constexpr int kNodes  = 512;
constexpr int kNOut   = 64;
constexpr int kBatch  = 32768;
constexpr int kHalf   = kBatch / 2;             // element stride between the pair
constexpr int kStrideF = 20;                    // floats per node slot (80 B)
constexpr int kLdsFloats = (kNodes + 3) * kStrideF + 4;  // prefetch overrun slack
constexpr float kScale = 2.8853900817779268f;   // 2*log2(e)

__device__ __forceinline__ v2f sp(float f) { v2f r; r.x = f; r.y = f; return r; }

// Issue the 5 ds_read_b128 for the node at LDS byte address `a` into set S.
#define PREF(S) {                                                             \
    asm volatile(                                                             \
      "ds_read_b128 %0, %5 offset:0\n\t"                                      \
      "ds_read_b128 %1, %5 offset:16\n\t"                                     \
      "ds_read_b128 %2, %5 offset:32\n\t"                                     \
      "ds_read_b128 %3, %5 offset:48\n\t"                                     \
      "ds_read_b128 %4, %5 offset:64"                                         \
      : "=&v"(q0[S]), "=&v"(q1[S]), "=&v"(q2[S]), "=&v"(q3[S]), "=&v"(q4[S])  \
      : "v"(a));                                                              \
    a += kStrideF * 4; }

// After PREF of node i+3, <=15 newer reads outstanding => lgkmcnt(15) means
// node i's 5 reads have landed (DS returns in-order; nothing else uses lgkm).
#define WAITQ(S)                                                              \
    asm volatile("s_waitcnt lgkmcnt(15)"                                      \
      : "+v"(q0[S]), "+v"(q1[S]), "+v"(q2[S]), "+v"(q3[S]), "+v"(q4[S]));

// Node i = g*16+K for BOTH elements (x=elem A, y=elem B of each v2f).
// A0 = oldest slot (weight j=0, overwritten), A15 = previous node's value
// (weight j=15, kept in the FINAL fma -> only op on each serial chain).
// q4 = (b*scale, r, -2r, pad). Chain: fma->exp2->add->rcp->fma.
#define NODE(K, A0,A1,A2,A3,A4,A5,A6,A7,A8,A9,A10,A11,A12,A13,A14,A15) {     \
    PREF(((K)+3)&3)                                                          \
    WAITQ((K)&3)                                                             \
    const int s = (K)&3;                                                     \
    v4f qa = q0[s], qb = q1[s], qc = q2[s], qd = q3[s], qm = q4[s];          \
    v2f p0 = __builtin_elementwise_fma(A0,  sp(qa.x), sp(qm.x));             \
    v2f p1 = A4  * sp(qb.x);                                                 \
    v2f p2 = A8  * sp(qc.x);                                                 \
    v2f p3 = A12 * sp(qd.x);                                                 \
    p0 = __builtin_elementwise_fma(A1,  sp(qa.y), p0);                       \
    p1 = __builtin_elementwise_fma(A5,  sp(qb.y), p1);                       \
    p2 = __builtin_elementwise_fma(A9,  sp(qc.y), p2);                       \
    p3 = __builtin_elementwise_fma(A13, sp(qd.y), p3);                       \
    p0 = __builtin_elementwise_fma(A2,  sp(qa.z), p0);                       \
    p1 = __builtin_elementwise_fma(A6,  sp(qb.z), p1);                       \
    p2 = __builtin_elementwise_fma(A10, sp(qc.z), p2);                       \
    p3 = __builtin_elementwise_fma(A14, sp(qd.z), p3);                       \
    p0 = __builtin_elementwise_fma(A3,  sp(qa.w), p0);                       \
    p1 = __builtin_elementwise_fma(A7,  sp(qb.w), p1);                       \
    p2 = __builtin_elementwise_fma(A11, sp(qc.w), p2);                       \
    v2f pre = (p0 + p1) + (p2 + p3);                                         \
    v2f acc = __builtin_elementwise_fma(A15, sp(qd.w), pre);                 \
    float eA = __builtin_amdgcn_exp2f(acc.x);                                \
    float eB = __builtin_amdgcn_exp2f(acc.y);                                \
    float uA = __builtin_amdgcn_rcpf(eA + 1.0f);                             \
    float uB = __builtin_amdgcn_rcpf(eB + 1.0f);                             \
    A0.x = fmaf(qm.z, uA, qm.y);                                             \
    A0.y = fmaf(qm.z, uB, qm.y); }

__global__ __launch_bounds__(64) void neat_fwd(
    const float* __restrict__ x,      // [B, 16]
    const float* __restrict__ w,      // [512, 16]
    const float* __restrict__ bias,   // [512]
    const float* __restrict__ resp,   // [512]
    float* __restrict__ out)          // [B, 64]
{
    __shared__ float lds[kLdsFloats];

    const int t = threadIdx.x;

    // ---- Stage params into LDS, pre-scaled by 2*log2(e) (64 threads) ----
    const float4* __restrict__ w4 = reinterpret_cast<const float4*>(w);
    #pragma unroll
    for (int j = 0; j < 32; ++j) {
        int i4 = t + j * 64;                  // [0, 2048)
        float4 v = w4[i4];
        int node = i4 >> 2, pos = (i4 & 3) << 2;
        float4 s = make_float4(v.x * kScale, v.y * kScale, v.z * kScale, v.w * kScale);
        *reinterpret_cast<float4*>(lds + node * kStrideF + pos) = s;
    }
    #pragma unroll
    for (int j = 0; j < 8; ++j) {
        int n = t + j * 64;
        float b = bias[n], r = resp[n];
        lds[n * kStrideF + 16] = b * kScale;
        lds[n * kStrideF + 17] = r;
        lds[n * kStrideF + 18] = -2.0f * r;
        lds[n * kStrideF + 19] = 0.0f;
    }

    // ---- Two batch elements per thread: e0 and e0 + 16384 ----
    const int e0 = blockIdx.x * 64 + t;
    const float4* __restrict__ xa = reinterpret_cast<const float4*>(x) + (size_t)e0 * 4;
    const float4* __restrict__ xb = xa + (size_t)kHalf * 4;
    float4 a0 = xa[0], a1 = xa[1], a2 = xa[2], a3 = xa[3];
    float4 b0 = xb[0], b1 = xb[1], b2 = xb[2], b3 = xb[3];
    v2f v0, v1, v2, v3, v4, v5, v6, v7, v8, v9, v10, v11, v12, v13, v14, v15;
    v0.x=a0.x; v1.x=a0.y; v2.x=a0.z; v3.x=a0.w; v4.x=a1.x; v5.x=a1.y; v6.x=a1.z; v7.x=a1.w;
    v8.x=a2.x; v9.x=a2.y; v10.x=a2.z; v11.x=a2.w; v12.x=a3.x; v13.x=a3.y; v14.x=a3.z; v15.x=a3.w;
    v0.y=b0.x; v1.y=b0.y; v2.y=b0.z; v3.y=b0.w; v4.y=b1.x; v5.y=b1.y; v6.y=b1.z; v7.y=b1.w;
    v8.y=b2.x; v9.y=b2.y; v10.y=b2.z; v11.y=b2.w; v12.y=b3.x; v13.y=b3.y; v14.y=b3.z; v15.y=b3.w;

    float* __restrict__ opA = out + (size_t)e0 * kNOut;
    float* __restrict__ opB = opA + (size_t)kHalf * kNOut;

    __syncthreads();   // drains staging ds_writes (lgkmcnt(0))

    // LDS byte address cursor (low 32 bits of the flat-cast LDS pointer).
    unsigned int a = (unsigned int)(unsigned long long)(&lds[0]);

    v4f q0[4], q1[4], q2[4], q3[4], q4[4];
    PREF(0) PREF(1) PREF(2)    // nodes 0,1,2 in flight

    #pragma unroll 1
    for (int g = 0; g < 32; ++g) {
        NODE( 0, v0 ,v1 ,v2 ,v3 ,v4 ,v5 ,v6 ,v7 ,v8 ,v9 ,v10,v11,v12,v13,v14,v15)
        NODE( 1, v1 ,v2 ,v3 ,v4 ,v5 ,v6 ,v7 ,v8 ,v9 ,v10,v11,v12,v13,v14,v15,v0 )
        NODE( 2, v2 ,v3 ,v4 ,v5 ,v6 ,v7 ,v8 ,v9 ,v10,v11,v12,v13,v14,v15,v0 ,v1 )
        NODE( 3, v3 ,v4 ,v5 ,v6 ,v7 ,v8 ,v9 ,v10,v11,v12,v13,v14,v15,v0 ,v1 ,v2 )
        NODE( 4, v4 ,v5 ,v6 ,v7 ,v8 ,v9 ,v10,v11,v12,v13,v14,v15,v0 ,v1 ,v2 ,v3 )
        NODE( 5, v5 ,v6 ,v7 ,v8 ,v9 ,v10,v11,v12,v13,v14,v15,v0 ,v1 ,v2 ,v3 ,v4 )
        NODE( 6, v6 ,v7 ,v8 ,v9 ,v10,v11,v12,v13,v14,v15,v0 ,v1 ,v2 ,v3 ,v4 ,v5 )
        NODE( 7, v7 ,v8 ,v9 ,v10,v11,v12,v13,v14,v15,v0 ,v1 ,v2 ,v3 ,v4 ,v5 ,v6 )
        NODE( 8, v8 ,v9 ,v10,v11,v12,v13,v14,v15,v0 ,v1 ,v2 ,v3 ,v4 ,v5 ,v6 ,v7 )
        NODE( 9, v9 ,v10,v11,v12,v13,v14,v15,v0 ,v1 ,v2 ,v3 ,v4 ,v5 ,v6 ,v7 ,v8 )
        NODE(10, v10,v11,v12,v13,v14,v15,v0 ,v1 ,v2 ,v3 ,v4 ,v5 ,v6 ,v7 ,v8 ,v9 )
        NODE(11, v11,v12,v13,v14,v15,v0 ,v1 ,v2 ,v3 ,v4 ,v5 ,v6 ,v7 ,v8 ,v9 ,v10)
        NODE(12, v12,v13,v14,v15,v0 ,v1 ,v2 ,v3 ,v4 ,v5 ,v6 ,v7 ,v8 ,v9 ,v10,v11)
        NODE(13, v13,v14,v15,v0 ,v1 ,v2 ,v3 ,v4 ,v5 ,v6 ,v7 ,v8 ,v9 ,v10,v11,v12)
        NODE(14, v14,v15,v0 ,v1 ,v2 ,v3 ,v4 ,v5 ,v6 ,v7 ,v8 ,v9 ,v10,v11,v12,v13)
        NODE(15, v15,v0 ,v1 ,v2 ,v3 ,v4 ,v5 ,v6 ,v7 ,v8 ,v9 ,v10,v11,v12,v13,v14)
        // After the group, window slot k == value of node g*16+k.
        if (g >= 28) {
            float4* oa = reinterpret_cast<float4*>(opA + (g - 28) * 16);
            oa[0] = make_float4(v0.x,  v1.x,  v2.x,  v3.x);
            oa[1] = make_float4(v4.x,  v5.x,  v6.x,  v7.x);
            oa[2] = make_float4(v8.x,  v9.x,  v10.x, v11.x);
            oa[3] = make_float4(v12.x, v13.x, v14.x, v15.x);
            float4* ob = reinterpret_cast<float4*>(opB + (g - 28) * 16);
            ob[0] = make_float4(v0.y,  v1.y,  v2.y,  v3.y);
            ob[1] = make_float4(v4.y,  v5.y,  v6.y,  v7.y);
            ob[2] = make_float4(v8.y,  v9.y,  v10.y, v11.y);
            ob[3] = make_float4(v12.y, v13.y, v14.y, v15.y);
        }
    }

    // Drain overrun prefetches (nodes 512..514).
    asm volatile("s_waitcnt lgkmcnt(0)" ::: "memory");
}

extern "C" void kernel_launch(void* const* d_in, const int* in_sizes, int n_in,
                              void* d_out, int out_size, void* d_ws, size_t ws_size,
                              hipStream_t stream) {
    const float* x    = (const float*)d_in[0];
    const float* w    = (const float*)d_in[1];
    const float* bias = (const float*)d_in[2];
    const float* resp = (const float*)d_in[3];
    float* out = (float*)d_out;
    // in_sizes[4] (src_idx) encodes the fixed windowed topology; hardcoded above.
    dim3 block(64);
    dim3 grid(kBatch / 128);   // 256 blocks x 64 thr x 2 elem -> 1 wave/CU
    hipLaunchKernelGGL(neat_fwd, grid, block, 0, stream, x, w, bias, resp, out);
}